// Round 3
// baseline (639.491 us; speedup 1.0000x reference)
//
#include <hip/hip_runtime.h>
#include <math.h>

#define IN_DIM 128
#define HID 64
#define OUT_DIM 128
#define ELL_W 64
#define NPART 8
constexpr float EPS = 1e-5f;

typedef short short8 __attribute__((ext_vector_type(8)));
typedef float f32x4  __attribute__((ext_vector_type(4)));
typedef int   i32x4  __attribute__((ext_vector_type(4)));

// ---------------------------------------------------------------------------
// ws layout (ELL path):
//   float [0,256)  column sums / sum-of-squares
//   int   work[8]  (work-stealing cursors, one per dst partition)
//   int   deg[N], ell[N*64]
//   bf16  qv[(N+64)*192]  (q 64 | v 128 interleaved per row), kb[(N+64)*64]
//   bf16  Bfrag[64*64*8]
// CSR fallback path keeps its own layout (deg at ws+256, no work array).
// ---------------------------------------------------------------------------

__device__ inline ushort f2bf(float x) {          // RNE float->bf16 bits
    __bf16 h = (__bf16)x;
    return *reinterpret_cast<ushort*>(&h);
}
__device__ inline short f2bfs(float x) {
    __bf16 h = (__bf16)x;
    return *reinterpret_cast<short*>(&h);
}
__device__ inline float bf2f(ushort u) {
    union { unsigned u; float f; } c; c.u = ((unsigned)u) << 16;
    return c.f;
}

__global__ __launch_bounds__(256) void stats_kernel(
    const float* __restrict__ feat, float* __restrict__ ws, int n_nodes)
{
    int col  = threadIdx.x & 127;
    int half = threadIdx.x >> 7;
    float sum = 0.f, sq = 0.f;
    for (int r = blockIdx.x * 2 + half; r < n_nodes; r += gridDim.x * 2) {
        float x = feat[r * IN_DIM + col];
        sum += x; sq += x * x;
    }
    __shared__ float redS[256], redQ[256];
    redS[threadIdx.x] = sum; redQ[threadIdx.x] = sq;
    __syncthreads();
    if (threadIdx.x < 128) {
        sum = redS[threadIdx.x] + redS[threadIdx.x + 128];
        sq  = redQ[threadIdx.x] + redQ[threadIdx.x + 128];
        unsafeAtomicAdd(&ws[col], sum);
        unsafeAtomicAdd(&ws[128 + col], sq);
    }
}

// One-time: lay out bf16([Wq|Wk|Wv]) in MFMA B-fragment order.
__global__ __launch_bounds__(256) void wprep(
    const float* __restrict__ Wq, const float* __restrict__ Wk,
    const float* __restrict__ Wv, ushort* __restrict__ Bfrag)
{
    int gid  = blockIdx.x * 256 + threadIdx.x;   // 0..4095
    int f    = gid >> 6;
    int lane = gid & 63;
    int kc = f & 3, ct = (f >> 2) & 3, w = f >> 4;
    int col   = w * 64 + ct * 16 + (lane & 15);
    int kbase = kc * 32 + (lane >> 4) * 8;
    ushort tmp[8];
    #pragma unroll
    for (int j = 0; j < 8; j++) {
        int k = kbase + j;
        float val;
        if (col < 64)       val = Wq[k * HID + col];
        else if (col < 128) val = Wk[k * HID + (col - 64)];
        else                val = Wv[k * OUT_DIM + (col - 128)];
        tmp[j] = f2bf(val);
    }
    ushort* d = &Bfrag[(f * 64 + lane) * 8];
    *(ushort4*)d       = make_ushort4(tmp[0], tmp[1], tmp[2], tmp[3]);
    *(ushort4*)(d + 4) = make_ushort4(tmp[4], tmp[5], tmp[6], tmp[7]);
}

// MFMA layernorm+GEMM. Output layout: qv rows (stride 192: q@0, v@64), kb rows.
__global__ __launch_bounds__(256) void mfma_qkv(
    const float* __restrict__ feat, const ushort* __restrict__ Bfrag,
    const float* __restrict__ bq,
    const float* __restrict__ gamma, const float* __restrict__ beta,
    const float* __restrict__ stats,
    ushort* __restrict__ qvb, ushort* __restrict__ kb,
    int n_nodes)
{
    __shared__ float sc[IN_DIM], sh[IN_DIM];
    int tid = threadIdx.x;
    if (tid < 128) {
        float inv_n = 1.0f / (float)n_nodes;
        float mean = stats[tid] * inv_n;
        float var  = stats[128 + tid] * inv_n - mean * mean;
        float s    = gamma[tid] * rsqrtf(var + EPS);
        sc[tid] = s; sh[tid] = beta[tid] - mean * s;
    }

    int w    = tid >> 6;
    int lane = tid & 63;
    int row0 = blockIdx.x * 64;
    int m    = lane & 15;
    int quad = lane >> 4;
    int nm1  = n_nodes - 1;

    short8 bfr[16];
    #pragma unroll
    for (int f = 0; f < 16; f++)
        bfr[f] = *(const short8*)&Bfrag[((w * 16 + f) * 64 + lane) * 8];

    __syncthreads();

    f32x4 acc[4][4] = {};   // [row-tile][col-tile]

    #pragma unroll
    for (int kc = 0; kc < 4; kc++) {
        int koff = kc * 32 + quad * 8;
        float4 sc0 = *(const float4*)&sc[koff];
        float4 sc1 = *(const float4*)&sc[koff + 4];
        float4 sh0 = *(const float4*)&sh[koff];
        float4 sh1 = *(const float4*)&sh[koff + 4];
        short8 afr[4];
        #pragma unroll
        for (int rt = 0; rt < 4; rt++) {
            int row = row0 + rt * 16 + m;
            row = row < nm1 ? row : nm1;            // clamp OOB reads
            const float* fp = &feat[(size_t)row * IN_DIM + koff];
            float4 x0 = *(const float4*)fp;
            float4 x1 = *(const float4*)(fp + 4);
            afr[rt][0] = f2bfs(x0.x * sc0.x + sh0.x);
            afr[rt][1] = f2bfs(x0.y * sc0.y + sh0.y);
            afr[rt][2] = f2bfs(x0.z * sc0.z + sh0.z);
            afr[rt][3] = f2bfs(x0.w * sc0.w + sh0.w);
            afr[rt][4] = f2bfs(x1.x * sc1.x + sh1.x);
            afr[rt][5] = f2bfs(x1.y * sc1.y + sh1.y);
            afr[rt][6] = f2bfs(x1.z * sc1.z + sh1.z);
            afr[rt][7] = f2bfs(x1.w * sc1.w + sh1.w);
        }
        #pragma unroll
        for (int rt = 0; rt < 4; rt++)
            #pragma unroll
            for (int ct = 0; ct < 4; ct++)
                acc[rt][ct] = __builtin_amdgcn_mfma_f32_16x16x32_bf16(
                    afr[rt], bfr[ct * 4 + kc], acc[rt][ct], 0, 0, 0);
    }

    // w==0: q -> qv@0 ; w==1: k -> kb ; w==2/3: v -> qv@64/128
    ushort* base; int ld, cl;
    if (w == 1)      { base = kb;  ld = HID; cl = 0; }
    else             { base = qvb; ld = 192; cl = (w == 0) ? 0 : 64 * (w - 1); }

    #pragma unroll
    for (int ct = 0; ct < 4; ct++) {
        int col = cl + ct * 16 + m;
        float bias = (w == 0) ? bq[ct * 16 + m] : 0.f;
        #pragma unroll
        for (int rt = 0; rt < 4; rt++) {
            int r0 = row0 + rt * 16 + quad * 4;
            #pragma unroll
            for (int r = 0; r < 4; r++)
                base[(size_t)(r0 + r) * ld + col] = f2bf(acc[rt][ct][r] + bias);
        }
    }
}

// ---------------- ELL build: XCC_ID-pinned dst partitions ------------------
// Each wave reads its REAL XCD id (HW_REG_XCC_ID, HW-verified 0-7 on MI355X)
// and drains dst-partition p==xcd via a work-stealing cursor, so partition p's
// ELL slice (3.2 MB) + deg slice (50 KB) is written from exactly one XCD's L2.
// After its own partition a wave helps drain the others through the same
// cursors -> correctness holds for ANY xcd distribution (pure locality hint).
__global__ __launch_bounds__(256) void fill_ell_xcd(
    const int* __restrict__ src, const int* __restrict__ dst,
    int* __restrict__ work, int* __restrict__ deg, int* __restrict__ ell,
    int n_edges, int part_size)
{
    int xcd;
    asm volatile("s_getreg_b32 %0, hwreg(HW_REG_XCC_ID)" : "=s"(xcd));
    xcd &= (NPART - 1);

    int lane = threadIdx.x & 63;
    const int CH = 2048;                       // edges per wave grab
    int n4 = n_edges >> 2;
    const i32x4* dst4 = reinterpret_cast<const i32x4*>(dst);
    const i32x4* src4 = reinterpret_cast<const i32x4*>(src);

    for (int pi = 0; pi < NPART; ++pi) {
        int p = (xcd + pi) & (NPART - 1);
        unsigned lo = (unsigned)(p * part_size);
        unsigned ps = (unsigned)part_size;
        for (;;) {
            // cheap monotonic gate (stale-low safe: atomic below re-checks)
            if (*(volatile int*)&work[p] >= n_edges) break;
            int base = 0;
            if (lane == 0) base = atomicAdd(&work[p], CH);
            base = __shfl(base, 0, 64);
            if (base >= n_edges) break;

            int i0 = base >> 2;
            int i1 = (base + CH) >> 2; if (i1 > n4) i1 = n4;
            for (int i = i0 + lane; i < i1; i += 64) {
                i32x4 d4 = __builtin_nontemporal_load(dst4 + i);
                i32x4 s4 = __builtin_nontemporal_load(src4 + i);
                #pragma unroll
                for (int j = 0; j < 4; j++) {
                    unsigned d = (unsigned)d4[j];
                    if (d - lo < ps) {
                        int pos = atomicAdd(&deg[d], 1);
                        if (pos < ELL_W) ell[(size_t)d * ELL_W + pos] = s4[j];
                    }
                }
            }
            // scalar tail (chunk overlapping the non-multiple-of-4 remainder)
            int t0 = base > (n4 << 2) ? base : (n4 << 2);
            int t1 = base + CH; if (t1 > n_edges) t1 = n_edges;
            for (int e = t0 + lane; e < t1; e += 64) {
                unsigned d = (unsigned)dst[e];
                if (d - lo < ps) {
                    int pos = atomicAdd(&deg[d], 1);
                    if (pos < ELL_W) ell[(size_t)d * ELL_W + pos] = src[e];
                }
            }
        }
    }
}

// ---------------- CSR fallback kernels (used if ws too small) ----------
__global__ __launch_bounds__(256) void hist_kernel(
    const int* __restrict__ dst, int* __restrict__ deg, int n_edges)
{
    int e = blockIdx.x * 256 + threadIdx.x;
    if (e < n_edges) atomicAdd(&deg[dst[e]], 1);
}

#define SCAN_B 256

__global__ __launch_bounds__(256) void scan_partial(
    const int* __restrict__ deg, int* __restrict__ part, int n)
{
    int chunk = (n + SCAN_B - 1) / SCAN_B;
    int lo = blockIdx.x * chunk;
    int hi = lo + chunk; if (hi > n) hi = n;
    int s = 0;
    for (int i = lo + threadIdx.x; i < hi; i += 256) s += deg[i];
    __shared__ int red[256];
    red[threadIdx.x] = s; __syncthreads();
    for (int d = 128; d; d >>= 1) {
        if (threadIdx.x < d) red[threadIdx.x] += red[threadIdx.x + d];
        __syncthreads();
    }
    if (threadIdx.x == 0) part[blockIdx.x] = red[0];
}

__global__ __launch_bounds__(256) void scan_combine(
    int* __restrict__ part, int* __restrict__ offsets, int n)
{
    __shared__ int tmp[256];
    int t = threadIdx.x;
    int v = part[t];
    tmp[t] = v; __syncthreads();
    for (int d = 1; d < 256; d <<= 1) {
        int cur = tmp[t];
        int add = (t >= d) ? tmp[t - d] : 0;
        __syncthreads();
        tmp[t] = cur + add;
        __syncthreads();
    }
    part[t] = tmp[t] - v;
    if (t == 255) offsets[n] = tmp[255];
}

__global__ __launch_bounds__(256) void scan_final(
    const int* __restrict__ deg, const int* __restrict__ part,
    int* __restrict__ offsets, int* __restrict__ cursor, int n)
{
    __shared__ int tmp[256];
    int t = threadIdx.x;
    int chunk = (n + SCAN_B - 1) / SCAN_B;
    int lo = blockIdx.x * chunk;
    int hi = lo + chunk; if (hi > n) hi = n;
    int base = part[blockIdx.x];
    for (int i0 = lo; i0 < hi; i0 += 256) {
        int i = i0 + t;
        int d = (i < hi) ? deg[i] : 0;
        tmp[t] = d; __syncthreads();
        for (int s = 1; s < 256; s <<= 1) {
            int cur = tmp[t];
            int add = (t >= s) ? tmp[t - s] : 0;
            __syncthreads();
            tmp[t] = cur + add;
            __syncthreads();
        }
        int excl = tmp[t] - d;
        int total = tmp[255];
        if (i < hi) { offsets[i] = base + excl; cursor[i] = base + excl; }
        base += total;
        __syncthreads();
    }
}

__global__ __launch_bounds__(256) void fill_kernel(
    const int* __restrict__ src, const int* __restrict__ dst,
    int* __restrict__ cursor, int* __restrict__ csr_src, int n_edges)
{
    int e = blockIdx.x * 256 + threadIdx.x;
    if (e < n_edges) {
        int d = dst[e];
        int pos = atomicAdd(&cursor[d], 1);
        csr_src[pos] = src[e];
    }
}

// ---------------- fused per-node gather core (8-wide edge groups) ------
// lane = sub*8 + h : sub in [0,8) picks the edge, h in [0,8) picks 8 q-dims
// and 16 v-dims. qv row: [q 64 | v 128] bf16, stride 192.
__device__ inline void gather_core(
    const int* __restrict__ row, int cnt, int node, int h, int sub,
    const ushort* __restrict__ qvb, const ushort* __restrict__ kb,
    const float* __restrict__ We, float* __restrict__ out)
{
    int ob = node * OUT_DIM + 16 * h;
    if (cnt == 0) {
        if (sub == 0) {
            float4 z = make_float4(0.f, 0.f, 0.f, 0.f);
            #pragma unroll
            for (int g = 0; g < 4; g++) *(float4*)&out[ob + 4 * g] = z;
        }
        return;
    }

    float kd[8], we[8];
    {
        short8 k8 = *(const short8*)&kb[node * HID + 8 * h];
        #pragma unroll
        for (int j = 0; j < 8; j++) kd[j] = bf2f((ushort)k8[j]);
        float4 wa = *(const float4*)&We[8 * h];
        float4 wb = *(const float4*)&We[8 * h + 4];
        we[0] = wa.x; we[1] = wa.y; we[2] = wa.z; we[3] = wa.w;
        we[4] = wb.x; we[5] = wb.y; we[6] = wb.z; we[7] = wb.w;
    }

    float o[16];
    #pragma unroll
    for (int j = 0; j < 16; j++) o[j] = 0.f;
    float ssum = 0.f;

    for (int p0 = 0; p0 < cnt; p0 += 8) {
        int p = p0 + sub;
        bool act = (p < cnt);
        int sN = row[act ? p : 0];
        const ushort* qv = qvb + (size_t)sN * 192;

        short8 q8 = *(const short8*)(qv + 8 * h);
        float t = 0.f;
        #pragma unroll
        for (int j = 0; j < 8; j++) {
            float x = bf2f((ushort)q8[j]) + kd[j];
            t += we[j] * __fdividef(1.f, 1.f + __expf(-x));
        }
        t += __shfl_xor(t, 1);
        t += __shfl_xor(t, 2);
        t += __shfl_xor(t, 4);

        float exv = act ? __expf(t) : 0.f;
        ssum += exv;

        short8 v0 = *(const short8*)(qv + 64 + 16 * h);
        short8 v1 = *(const short8*)(qv + 72 + 16 * h);
        #pragma unroll
        for (int j = 0; j < 8; j++) {
            o[j]     += exv * bf2f((ushort)v0[j]);
            o[8 + j] += exv * bf2f((ushort)v1[j]);
        }
    }

    #pragma unroll
    for (int mm = 8; mm <= 32; mm <<= 1) {
        ssum += __shfl_xor(ssum, mm);
        #pragma unroll
        for (int j = 0; j < 16; j++) o[j] += __shfl_xor(o[j], mm);
    }

    if (sub == 0) {
        float inv = (ssum > 0.f) ? __fdividef(1.f, ssum) : 0.f;
        #pragma unroll
        for (int g = 0; g < 4; g++) {
            float4 r = make_float4(o[4 * g] * inv, o[4 * g + 1] * inv,
                                   o[4 * g + 2] * inv, o[4 * g + 3] * inv);
            *(float4*)&out[ob + 4 * g] = r;
        }
    }
}

__global__ __launch_bounds__(256) void gather_ell(
    const int* __restrict__ deg, const int* __restrict__ ell,
    const ushort* __restrict__ qvb, const ushort* __restrict__ kb,
    const float* __restrict__ We,
    float* __restrict__ out, int n_nodes)
{
    int node = (blockIdx.x * 256 + threadIdx.x) >> 6;
    int lane = threadIdx.x & 63;
    if (node >= n_nodes) return;
    int cnt = deg[node];
    cnt = cnt < ELL_W ? cnt : ELL_W;
    gather_core(&ell[(size_t)node * ELL_W], cnt, node,
                lane & 7, lane >> 3, qvb, kb, We, out);
}

__global__ __launch_bounds__(256) void gather_csr(
    const int* __restrict__ offsets, const int* __restrict__ csr_src,
    const ushort* __restrict__ qvb, const ushort* __restrict__ kb,
    const float* __restrict__ We,
    float* __restrict__ out, int n_nodes)
{
    int node = (blockIdx.x * 256 + threadIdx.x) >> 6;
    int lane = threadIdx.x & 63;
    if (node >= n_nodes) return;
    int beg = offsets[node];
    int cnt = offsets[node + 1] - beg;
    gather_core(&csr_src[beg], cnt, node,
                lane & 7, lane >> 3, qvb, kb, We, out);
}

extern "C" void kernel_launch(void* const* d_in, const int* in_sizes, int n_in,
                              void* d_out, int out_size, void* d_ws, size_t ws_size,
                              hipStream_t stream)
{
    const float* feat  = (const float*)d_in[0];
    const int*   src   = (const int*)d_in[1];
    const int*   dst   = (const int*)d_in[2];
    const float* gamma = (const float*)d_in[3];
    const float* beta  = (const float*)d_in[4];
    const float* Wq    = (const float*)d_in[5];
    const float* bq    = (const float*)d_in[6];
    const float* Wk    = (const float*)d_in[7];
    const float* Wv    = (const float*)d_in[8];
    const float* We    = (const float*)d_in[9];

    int n_nodes = in_sizes[0] / IN_DIM;
    int n_edges = in_sizes[1];
    int n_pad   = n_nodes + 64;             // store slack for branchless epilogue
    size_t bfelems = (size_t)n_pad * (192 + HID) + 64 * 64 * 8;

    float* ws = (float*)d_ws;

    // ELL-path workspace requirement (stats 256f + work 8i + deg/ell + bf16)
    size_t ell_floats = 264 + (size_t)n_nodes * (1 + ELL_W) + 4;
    size_t ell_need   = (ell_floats + (bfelems + 1) / 2) * 4;

    int eb = (n_edges + 255) / 256;

    if (ws_size >= ell_need) {
        // ---------------- ELL path: 6 dispatches ----------------
        int* work = (int*)(ws + 256);
        int* deg  = work + NPART;
        int* ell  = deg + n_nodes;
        size_t off = 264 + (size_t)n_nodes * (1 + ELL_W);
        off = (off + 3) & ~(size_t)3;
        ushort* qvb   = (ushort*)(ws + off);
        ushort* kb    = qvb + (size_t)n_pad * 192;
        ushort* Bfrag = kb + (size_t)n_pad * HID;

        int part_size = (n_nodes + NPART - 1) / NPART;

        hipMemsetAsync(ws, 0, (264 + (size_t)n_nodes) * sizeof(float), stream);
        stats_kernel<<<256, 256, 0, stream>>>(feat, ws, n_nodes);
        wprep<<<16, 256, 0, stream>>>(Wq, Wk, Wv, Bfrag);
        fill_ell_xcd<<<1024, 256, 0, stream>>>(
            src, dst, work, deg, ell, n_edges, part_size);
        mfma_qkv<<<(n_nodes + 63) / 64, 256, 0, stream>>>(
            feat, Bfrag, bq, gamma, beta, ws, qvb, kb, n_nodes);
        long long g_threads = (long long)n_nodes * 64;
        gather_ell<<<(int)((g_threads + 255) / 256), 256, 0, stream>>>(
            deg, ell, qvb, kb, We, (float*)d_out, n_nodes);
    } else {
        // ---------------- CSR fallback: 10 dispatches ----------------
        int* deg     = (int*)(ws + 256);
        int* offsets = deg + n_nodes;
        int* cursor  = offsets + n_nodes + 1;
        int* part    = cursor + n_nodes;
        int* csr_src = part + SCAN_B;
        size_t off = 256 + 3 * (size_t)n_nodes + 1 + SCAN_B + (size_t)n_edges;
        off = (off + 3) & ~(size_t)3;
        ushort* qvb   = (ushort*)(ws + off);
        ushort* kb    = qvb + (size_t)n_pad * 192;
        ushort* Bfrag = kb + (size_t)n_pad * HID;

        hipMemsetAsync(ws, 0, (256 + (size_t)n_nodes) * sizeof(float), stream);
        stats_kernel<<<256, 256, 0, stream>>>(feat, ws, n_nodes);
        wprep<<<16, 256, 0, stream>>>(Wq, Wk, Wv, Bfrag);
        hist_kernel<<<eb, 256, 0, stream>>>(dst, deg, n_edges);
        scan_partial<<<SCAN_B, 256, 0, stream>>>(deg, part, n_nodes);
        scan_combine<<<1, 256, 0, stream>>>(part, offsets, n_nodes);
        scan_final<<<SCAN_B, 256, 0, stream>>>(deg, part, offsets, cursor, n_nodes);
        fill_kernel<<<eb, 256, 0, stream>>>(src, dst, cursor, csr_src, n_edges);
        mfma_qkv<<<(n_nodes + 63) / 64, 256, 0, stream>>>(
            feat, Bfrag, bq, gamma, beta, ws, qvb, kb, n_nodes);
        long long g_threads = (long long)n_nodes * 64;
        gather_csr<<<(int)((g_threads + 255) / 256), 256, 0, stream>>>(
            offsets, csr_src, qvb, kb, We, (float*)d_out, n_nodes);
    }
}

// Round 4
// 500.076 us; speedup vs baseline: 1.2788x; 1.2788x over previous
//
#include <hip/hip_runtime.h>
#include <math.h>

#define IN_DIM 128
#define HID 64
#define OUT_DIM 128
#define ELL_W 64
constexpr float EPS = 1e-5f;

typedef short short8 __attribute__((ext_vector_type(8)));
typedef float f32x4  __attribute__((ext_vector_type(4)));
typedef int   i32x4  __attribute__((ext_vector_type(4)));

// ---------------------------------------------------------------------------
// ws layout (ELL path):
//   float [0,256)  column sums / sum-of-squares
//   int   deg[N], ell[N*64]
//   bf16  qv[(N+64)*192]  (q 64 | v 128 per row, 384B rows), kb[(N+64)*64]
//   bf16  Bfrag[64*64*8]
// CSR fallback path keeps its own layout.
// ---------------------------------------------------------------------------

__device__ inline ushort f2bf(float x) {          // RNE float->bf16 bits
    __bf16 h = (__bf16)x;
    return *reinterpret_cast<ushort*>(&h);
}
__device__ inline short f2bfs(float x) {
    __bf16 h = (__bf16)x;
    return *reinterpret_cast<short*>(&h);
}
__device__ inline float bf2f(ushort u) {
    union { unsigned u; float f; } c; c.u = ((unsigned)u) << 16;
    return c.f;
}

__global__ __launch_bounds__(256) void stats_kernel(
    const float* __restrict__ feat, float* __restrict__ ws, int n_nodes)
{
    int col  = threadIdx.x & 127;
    int half = threadIdx.x >> 7;
    float sum = 0.f, sq = 0.f;
    for (int r = blockIdx.x * 2 + half; r < n_nodes; r += gridDim.x * 2) {
        float x = feat[r * IN_DIM + col];
        sum += x; sq += x * x;
    }
    __shared__ float redS[256], redQ[256];
    redS[threadIdx.x] = sum; redQ[threadIdx.x] = sq;
    __syncthreads();
    if (threadIdx.x < 128) {
        sum = redS[threadIdx.x] + redS[threadIdx.x + 128];
        sq  = redQ[threadIdx.x] + redQ[threadIdx.x + 128];
        unsafeAtomicAdd(&ws[col], sum);
        unsafeAtomicAdd(&ws[128 + col], sq);
    }
}

// One-time: lay out bf16([Wq|Wk|Wv]) in MFMA B-fragment order.
__global__ __launch_bounds__(256) void wprep(
    const float* __restrict__ Wq, const float* __restrict__ Wk,
    const float* __restrict__ Wv, ushort* __restrict__ Bfrag)
{
    int gid  = blockIdx.x * 256 + threadIdx.x;   // 0..4095
    int f    = gid >> 6;
    int lane = gid & 63;
    int kc = f & 3, ct = (f >> 2) & 3, w = f >> 4;
    int col   = w * 64 + ct * 16 + (lane & 15);
    int kbase = kc * 32 + (lane >> 4) * 8;
    ushort tmp[8];
    #pragma unroll
    for (int j = 0; j < 8; j++) {
        int k = kbase + j;
        float val;
        if (col < 64)       val = Wq[k * HID + col];
        else if (col < 128) val = Wk[k * HID + (col - 64)];
        else                val = Wv[k * OUT_DIM + (col - 128)];
        tmp[j] = f2bf(val);
    }
    ushort* d = &Bfrag[(f * 64 + lane) * 8];
    *(ushort4*)d       = make_ushort4(tmp[0], tmp[1], tmp[2], tmp[3]);
    *(ushort4*)(d + 4) = make_ushort4(tmp[4], tmp[5], tmp[6], tmp[7]);
}

// MFMA layernorm+GEMM. Output layout: qv rows (stride 192: q@0, v@64), kb rows.
__global__ __launch_bounds__(256) void mfma_qkv(
    const float* __restrict__ feat, const ushort* __restrict__ Bfrag,
    const float* __restrict__ bq,
    const float* __restrict__ gamma, const float* __restrict__ beta,
    const float* __restrict__ stats,
    ushort* __restrict__ qvb, ushort* __restrict__ kb,
    int n_nodes)
{
    __shared__ float sc[IN_DIM], sh[IN_DIM];
    int tid = threadIdx.x;
    if (tid < 128) {
        float inv_n = 1.0f / (float)n_nodes;
        float mean = stats[tid] * inv_n;
        float var  = stats[128 + tid] * inv_n - mean * mean;
        float s    = gamma[tid] * rsqrtf(var + EPS);
        sc[tid] = s; sh[tid] = beta[tid] - mean * s;
    }

    int w    = tid >> 6;
    int lane = tid & 63;
    int row0 = blockIdx.x * 64;
    int m    = lane & 15;
    int quad = lane >> 4;
    int nm1  = n_nodes - 1;

    short8 bfr[16];
    #pragma unroll
    for (int f = 0; f < 16; f++)
        bfr[f] = *(const short8*)&Bfrag[((w * 16 + f) * 64 + lane) * 8];

    __syncthreads();

    f32x4 acc[4][4] = {};   // [row-tile][col-tile]

    #pragma unroll
    for (int kc = 0; kc < 4; kc++) {
        int koff = kc * 32 + quad * 8;
        float4 sc0 = *(const float4*)&sc[koff];
        float4 sc1 = *(const float4*)&sc[koff + 4];
        float4 sh0 = *(const float4*)&sh[koff];
        float4 sh1 = *(const float4*)&sh[koff + 4];
        short8 afr[4];
        #pragma unroll
        for (int rt = 0; rt < 4; rt++) {
            int row = row0 + rt * 16 + m;
            row = row < nm1 ? row : nm1;            // clamp OOB reads
            const float* fp = &feat[(size_t)row * IN_DIM + koff];
            float4 x0 = *(const float4*)fp;
            float4 x1 = *(const float4*)(fp + 4);
            afr[rt][0] = f2bfs(x0.x * sc0.x + sh0.x);
            afr[rt][1] = f2bfs(x0.y * sc0.y + sh0.y);
            afr[rt][2] = f2bfs(x0.z * sc0.z + sh0.z);
            afr[rt][3] = f2bfs(x0.w * sc0.w + sh0.w);
            afr[rt][4] = f2bfs(x1.x * sc1.x + sh1.x);
            afr[rt][5] = f2bfs(x1.y * sc1.y + sh1.y);
            afr[rt][6] = f2bfs(x1.z * sc1.z + sh1.z);
            afr[rt][7] = f2bfs(x1.w * sc1.w + sh1.w);
        }
        #pragma unroll
        for (int rt = 0; rt < 4; rt++)
            #pragma unroll
            for (int ct = 0; ct < 4; ct++)
                acc[rt][ct] = __builtin_amdgcn_mfma_f32_16x16x32_bf16(
                    afr[rt], bfr[ct * 4 + kc], acc[rt][ct], 0, 0, 0);
    }

    // w==0: q -> qv@0 ; w==1: k -> kb ; w==2/3: v -> qv@64/128
    ushort* base; int ld, cl;
    if (w == 1)      { base = kb;  ld = HID; cl = 0; }
    else             { base = qvb; ld = 192; cl = (w == 0) ? 0 : 64 * (w - 1); }

    #pragma unroll
    for (int ct = 0; ct < 4; ct++) {
        int col = cl + ct * 16 + m;
        float bias = (w == 0) ? bq[ct * 16 + m] : 0.f;
        #pragma unroll
        for (int rt = 0; rt < 4; rt++) {
            int r0 = row0 + rt * 16 + quad * 4;
            #pragma unroll
            for (int r = 0; r < 4; r++)
                base[(size_t)(r0 + r) * ld + col] = f2bf(acc[rt][ct][r] + bias);
        }
    }
}

// ---------------- ELL build: single pass, atomic ELL store -----------------
// Evidence (r0 counters): scattered plain 4B stores cost a full 64B dirty-line
// writeback each (WRITE_SIZE 96.5MB = 1.6M x 64B), while the 1.6M deg atomics
// added ~no write traffic (atomics resolve at the coherence point without
// dirtying a private-L2 line per op). So: store the ELL entry with atomicExch
// instead of a plain store. Single pass, NT vector loads of src/dst.
__global__ __launch_bounds__(256) void fill_ell(
    const int* __restrict__ src, const int* __restrict__ dst,
    int* __restrict__ deg, int* __restrict__ ell, int n_edges)
{
    int idx    = blockIdx.x * 256 + threadIdx.x;
    int stride = gridDim.x * 256;
    int n4     = n_edges >> 2;

    const i32x4* dst4 = reinterpret_cast<const i32x4*>(dst);
    const i32x4* src4 = reinterpret_cast<const i32x4*>(src);

    for (int i = idx; i < n4; i += stride) {
        i32x4 d4 = __builtin_nontemporal_load(dst4 + i);
        i32x4 s4 = __builtin_nontemporal_load(src4 + i);
        #pragma unroll
        for (int j = 0; j < 4; j++) {
            int d = d4[j];
            int pos = atomicAdd(&deg[d], 1);
            if (pos < ELL_W) atomicExch(&ell[(size_t)d * ELL_W + pos], s4[j]);
        }
    }
    for (int e = (n4 << 2) + idx; e < n_edges; e += stride) {
        int d = dst[e];
        int pos = atomicAdd(&deg[d], 1);
        if (pos < ELL_W) atomicExch(&ell[(size_t)d * ELL_W + pos], src[e]);
    }
}

// ---------------- CSR fallback kernels (used if ws too small) ----------
__global__ __launch_bounds__(256) void hist_kernel(
    const int* __restrict__ dst, int* __restrict__ deg, int n_edges)
{
    int e = blockIdx.x * 256 + threadIdx.x;
    if (e < n_edges) atomicAdd(&deg[dst[e]], 1);
}

#define SCAN_B 256

__global__ __launch_bounds__(256) void scan_partial(
    const int* __restrict__ deg, int* __restrict__ part, int n)
{
    int chunk = (n + SCAN_B - 1) / SCAN_B;
    int lo = blockIdx.x * chunk;
    int hi = lo + chunk; if (hi > n) hi = n;
    int s = 0;
    for (int i = lo + threadIdx.x; i < hi; i += 256) s += deg[i];
    __shared__ int red[256];
    red[threadIdx.x] = s; __syncthreads();
    for (int d = 128; d; d >>= 1) {
        if (threadIdx.x < d) red[threadIdx.x] += red[threadIdx.x + d];
        __syncthreads();
    }
    if (threadIdx.x == 0) part[blockIdx.x] = red[0];
}

__global__ __launch_bounds__(256) void scan_combine(
    int* __restrict__ part, int* __restrict__ offsets, int n)
{
    __shared__ int tmp[256];
    int t = threadIdx.x;
    int v = part[t];
    tmp[t] = v; __syncthreads();
    for (int d = 1; d < 256; d <<= 1) {
        int cur = tmp[t];
        int add = (t >= d) ? tmp[t - d] : 0;
        __syncthreads();
        tmp[t] = cur + add;
        __syncthreads();
    }
    part[t] = tmp[t] - v;
    if (t == 255) offsets[n] = tmp[255];
}

__global__ __launch_bounds__(256) void scan_final(
    const int* __restrict__ deg, const int* __restrict__ part,
    int* __restrict__ offsets, int* __restrict__ cursor, int n)
{
    __shared__ int tmp[256];
    int t = threadIdx.x;
    int chunk = (n + SCAN_B - 1) / SCAN_B;
    int lo = blockIdx.x * chunk;
    int hi = lo + chunk; if (hi > n) hi = n;
    int base = part[blockIdx.x];
    for (int i0 = lo; i0 < hi; i0 += 256) {
        int i = i0 + t;
        int d = (i < hi) ? deg[i] : 0;
        tmp[t] = d; __syncthreads();
        for (int s = 1; s < 256; s <<= 1) {
            int cur = tmp[t];
            int add = (t >= s) ? tmp[t - s] : 0;
            __syncthreads();
            tmp[t] = cur + add;
            __syncthreads();
        }
        int excl = tmp[t] - d;
        int total = tmp[255];
        if (i < hi) { offsets[i] = base + excl; cursor[i] = base + excl; }
        base += total;
        __syncthreads();
    }
}

__global__ __launch_bounds__(256) void fill_kernel(
    const int* __restrict__ src, const int* __restrict__ dst,
    int* __restrict__ cursor, int* __restrict__ csr_src, int n_edges)
{
    int e = blockIdx.x * 256 + threadIdx.x;
    if (e < n_edges) {
        int d = dst[e];
        int pos = atomicAdd(&cursor[d], 1);
        csr_src[pos] = src[e];
    }
}

// ---------------- fused per-node gather core (8-wide edge groups) ------
// lane = sub*8 + h : sub in [0,8) picks the edge, h in [0,8) picks 8 q-dims
// and 16 v-dims. qv row: [q 64 | v 128] bf16, stride 192 (384B, line-aligned).
__device__ inline void gather_core(
    const int* __restrict__ row, int cnt, int node, int h, int sub,
    const ushort* __restrict__ qvb, const ushort* __restrict__ kb,
    const float* __restrict__ We, float* __restrict__ out)
{
    int ob = node * OUT_DIM + 16 * h;
    if (cnt == 0) {
        if (sub == 0) {
            float4 z = make_float4(0.f, 0.f, 0.f, 0.f);
            #pragma unroll
            for (int g = 0; g < 4; g++) *(float4*)&out[ob + 4 * g] = z;
        }
        return;
    }

    float kd[8], we[8];
    {
        short8 k8 = *(const short8*)&kb[node * HID + 8 * h];
        #pragma unroll
        for (int j = 0; j < 8; j++) kd[j] = bf2f((ushort)k8[j]);
        float4 wa = *(const float4*)&We[8 * h];
        float4 wb = *(const float4*)&We[8 * h + 4];
        we[0] = wa.x; we[1] = wa.y; we[2] = wa.z; we[3] = wa.w;
        we[4] = wb.x; we[5] = wb.y; we[6] = wb.z; we[7] = wb.w;
    }

    float o[16];
    #pragma unroll
    for (int j = 0; j < 16; j++) o[j] = 0.f;
    float ssum = 0.f;

    for (int p0 = 0; p0 < cnt; p0 += 8) {
        int p = p0 + sub;
        bool act = (p < cnt);
        int sN = row[act ? p : 0];
        const ushort* qv = qvb + (size_t)sN * 192;

        short8 q8 = *(const short8*)(qv + 8 * h);
        float t = 0.f;
        #pragma unroll
        for (int j = 0; j < 8; j++) {
            float x = bf2f((ushort)q8[j]) + kd[j];
            t += we[j] * __fdividef(1.f, 1.f + __expf(-x));
        }
        t += __shfl_xor(t, 1);
        t += __shfl_xor(t, 2);
        t += __shfl_xor(t, 4);

        float exv = act ? __expf(t) : 0.f;
        ssum += exv;

        short8 v0 = *(const short8*)(qv + 64 + 16 * h);
        short8 v1 = *(const short8*)(qv + 72 + 16 * h);
        #pragma unroll
        for (int j = 0; j < 8; j++) {
            o[j]     += exv * bf2f((ushort)v0[j]);
            o[8 + j] += exv * bf2f((ushort)v1[j]);
        }
    }

    #pragma unroll
    for (int mm = 8; mm <= 32; mm <<= 1) {
        ssum += __shfl_xor(ssum, mm);
        #pragma unroll
        for (int j = 0; j < 16; j++) o[j] += __shfl_xor(o[j], mm);
    }

    if (sub == 0) {
        float inv = (ssum > 0.f) ? __fdividef(1.f, ssum) : 0.f;
        #pragma unroll
        for (int g = 0; g < 4; g++) {
            float4 r = make_float4(o[4 * g] * inv, o[4 * g + 1] * inv,
                                   o[4 * g + 2] * inv, o[4 * g + 3] * inv);
            *(float4*)&out[ob + 4 * g] = r;
        }
    }
}

__global__ __launch_bounds__(256) void gather_ell(
    const int* __restrict__ deg, const int* __restrict__ ell,
    const ushort* __restrict__ qvb, const ushort* __restrict__ kb,
    const float* __restrict__ We,
    float* __restrict__ out, int n_nodes)
{
    int node = (blockIdx.x * 256 + threadIdx.x) >> 6;
    int lane = threadIdx.x & 63;
    if (node >= n_nodes) return;
    int cnt = deg[node];
    cnt = cnt < ELL_W ? cnt : ELL_W;
    gather_core(&ell[(size_t)node * ELL_W], cnt, node,
                lane & 7, lane >> 3, qvb, kb, We, out);
}

__global__ __launch_bounds__(256) void gather_csr(
    const int* __restrict__ offsets, const int* __restrict__ csr_src,
    const ushort* __restrict__ qvb, const ushort* __restrict__ kb,
    const float* __restrict__ We,
    float* __restrict__ out, int n_nodes)
{
    int node = (blockIdx.x * 256 + threadIdx.x) >> 6;
    int lane = threadIdx.x & 63;
    if (node >= n_nodes) return;
    int beg = offsets[node];
    int cnt = offsets[node + 1] - beg;
    gather_core(&csr_src[beg], cnt, node,
                lane & 7, lane >> 3, qvb, kb, We, out);
}

extern "C" void kernel_launch(void* const* d_in, const int* in_sizes, int n_in,
                              void* d_out, int out_size, void* d_ws, size_t ws_size,
                              hipStream_t stream)
{
    const float* feat  = (const float*)d_in[0];
    const int*   src   = (const int*)d_in[1];
    const int*   dst   = (const int*)d_in[2];
    const float* gamma = (const float*)d_in[3];
    const float* beta  = (const float*)d_in[4];
    const float* Wq    = (const float*)d_in[5];
    const float* bq    = (const float*)d_in[6];
    const float* Wk    = (const float*)d_in[7];
    const float* Wv    = (const float*)d_in[8];
    const float* We    = (const float*)d_in[9];

    int n_nodes = in_sizes[0] / IN_DIM;
    int n_edges = in_sizes[1];
    int n_pad   = n_nodes + 64;             // store slack for branchless epilogue
    size_t bfelems = (size_t)n_pad * (192 + HID) + 64 * 64 * 8;

    float* ws = (float*)d_ws;

    // ELL-path workspace requirement (stats 256f + deg/ell + bf16)
    size_t ell_floats = 256 + (size_t)n_nodes * (1 + ELL_W) + 4;
    size_t ell_need   = (ell_floats + (bfelems + 1) / 2) * 4;

    int eb = (n_edges + 255) / 256;

    if (ws_size >= ell_need) {
        // ---------------- ELL path: 6 dispatches ----------------
        int* deg = (int*)(ws + 256);
        int* ell = deg + n_nodes;
        size_t off = 256 + (size_t)n_nodes * (1 + ELL_W);
        off = (off + 3) & ~(size_t)3;
        ushort* qvb   = (ushort*)(ws + off);
        ushort* kb    = qvb + (size_t)n_pad * 192;
        ushort* Bfrag = kb + (size_t)n_pad * HID;

        hipMemsetAsync(ws, 0, (256 + (size_t)n_nodes) * sizeof(float), stream);
        stats_kernel<<<256, 256, 0, stream>>>(feat, ws, n_nodes);
        wprep<<<16, 256, 0, stream>>>(Wq, Wk, Wv, Bfrag);
        fill_ell<<<1024, 256, 0, stream>>>(src, dst, deg, ell, n_edges);
        mfma_qkv<<<(n_nodes + 63) / 64, 256, 0, stream>>>(
            feat, Bfrag, bq, gamma, beta, ws, qvb, kb, n_nodes);
        long long g_threads = (long long)n_nodes * 64;
        gather_ell<<<(int)((g_threads + 255) / 256), 256, 0, stream>>>(
            deg, ell, qvb, kb, We, (float*)d_out, n_nodes);
    } else {
        // ---------------- CSR fallback: 10 dispatches ----------------
        int* deg     = (int*)(ws + 256);
        int* offsets = deg + n_nodes;
        int* cursor  = offsets + n_nodes + 1;
        int* part    = cursor + n_nodes;
        int* csr_src = part + SCAN_B;
        size_t off = 256 + 3 * (size_t)n_nodes + 1 + SCAN_B + (size_t)n_edges;
        off = (off + 3) & ~(size_t)3;
        ushort* qvb   = (ushort*)(ws + off);
        ushort* kb    = qvb + (size_t)n_pad * 192;
        ushort* Bfrag = kb + (size_t)n_pad * HID;

        hipMemsetAsync(ws, 0, (256 + (size_t)n_nodes) * sizeof(float), stream);
        stats_kernel<<<256, 256, 0, stream>>>(feat, ws, n_nodes);
        wprep<<<16, 256, 0, stream>>>(Wq, Wk, Wv, Bfrag);
        hist_kernel<<<eb, 256, 0, stream>>>(dst, deg, n_edges);
        scan_partial<<<SCAN_B, 256, 0, stream>>>(deg, part, n_nodes);
        scan_combine<<<1, 256, 0, stream>>>(part, offsets, n_nodes);
        scan_final<<<SCAN_B, 256, 0, stream>>>(deg, part, offsets, cursor, n_nodes);
        fill_kernel<<<eb, 256, 0, stream>>>(src, dst, cursor, csr_src, n_edges);
        mfma_qkv<<<(n_nodes + 63) / 64, 256, 0, stream>>>(
            feat, Bfrag, bq, gamma, beta, ws, qvb, kb, n_nodes);
        long long g_threads = (long long)n_nodes * 64;
        gather_csr<<<(int)((g_threads + 255) / 256), 256, 0, stream>>>(
            offsets, csr_src, qvb, kb, We, (float*)d_out, n_nodes);
    }
}

// Round 5
// 488.931 us; speedup vs baseline: 1.3079x; 1.0228x over previous
//
#include <hip/hip_runtime.h>
#include <math.h>

#define IN_DIM 128
#define HID 64
#define OUT_DIM 128
#define ELL_W 64
#define NWG 64          // binning workgroups (hist/scatter) -> 16-entry runs
#define SCAN_B 256
constexpr float EPS = 1e-5f;

typedef short short8 __attribute__((ext_vector_type(8)));
typedef float f32x4  __attribute__((ext_vector_type(4)));

// ---------------------------------------------------------------------------
// ws layout:
//   float [0,256)   column sums / sum-of-squares
//   int   histT[NBK*NWG]          per-(bucket,WG) edge counts (bucket-major)
//   int   offs [NBK*NWG+1]        exclusive scan of histT
//   int   part [SCAN_B]           scan partials
//   int   cursor[NBK*NWG+1]       scan_final scratch
//   int   packed[n_edges]         (dst&63)<<26 | src, grouped by bucket
//   bf16  qv[(N+64)*192]  (q 64 | v 128 per row, 384B), kb[(N+64)*64]
//   bf16  Bfrag[64*64*8]
// No global atomics anywhere in the edge pipeline; no scattered 4B stores.
// ---------------------------------------------------------------------------

__device__ inline ushort f2bf(float x) {          // RNE float->bf16 bits
    __bf16 h = (__bf16)x;
    return *reinterpret_cast<ushort*>(&h);
}
__device__ inline short f2bfs(float x) {
    __bf16 h = (__bf16)x;
    return *reinterpret_cast<short*>(&h);
}
__device__ inline float bf2f(ushort u) {
    union { unsigned u; float f; } c; c.u = ((unsigned)u) << 16;
    return c.f;
}
__device__ inline float4 bf4_to_f4(ushort4 u) {
    return make_float4(bf2f(u.x), bf2f(u.y), bf2f(u.z), bf2f(u.w));
}

__global__ __launch_bounds__(256) void stats_kernel(
    const float* __restrict__ feat, float* __restrict__ ws, int n_nodes)
{
    int col  = threadIdx.x & 127;
    int half = threadIdx.x >> 7;
    float sum = 0.f, sq = 0.f;
    for (int r = blockIdx.x * 2 + half; r < n_nodes; r += gridDim.x * 2) {
        float x = feat[r * IN_DIM + col];
        sum += x; sq += x * x;
    }
    __shared__ float redS[256], redQ[256];
    redS[threadIdx.x] = sum; redQ[threadIdx.x] = sq;
    __syncthreads();
    if (threadIdx.x < 128) {
        sum = redS[threadIdx.x] + redS[threadIdx.x + 128];
        sq  = redQ[threadIdx.x] + redQ[threadIdx.x + 128];
        unsafeAtomicAdd(&ws[col], sum);
        unsafeAtomicAdd(&ws[128 + col], sq);
    }
}

// One-time: lay out bf16([Wq|Wk|Wv]) in MFMA B-fragment order.
__global__ __launch_bounds__(256) void wprep(
    const float* __restrict__ Wq, const float* __restrict__ Wk,
    const float* __restrict__ Wv, ushort* __restrict__ Bfrag)
{
    int gid  = blockIdx.x * 256 + threadIdx.x;   // 0..4095
    int f    = gid >> 6;
    int lane = gid & 63;
    int kc = f & 3, ct = (f >> 2) & 3, w = f >> 4;
    int col   = w * 64 + ct * 16 + (lane & 15);
    int kbase = kc * 32 + (lane >> 4) * 8;
    ushort tmp[8];
    #pragma unroll
    for (int j = 0; j < 8; j++) {
        int k = kbase + j;
        float val;
        if (col < 64)       val = Wq[k * HID + col];
        else if (col < 128) val = Wk[k * HID + (col - 64)];
        else                val = Wv[k * OUT_DIM + (col - 128)];
        tmp[j] = f2bf(val);
    }
    ushort* d = &Bfrag[(f * 64 + lane) * 8];
    *(ushort4*)d       = make_ushort4(tmp[0], tmp[1], tmp[2], tmp[3]);
    *(ushort4*)(d + 4) = make_ushort4(tmp[4], tmp[5], tmp[6], tmp[7]);
}

// MFMA layernorm+GEMM. Output layout: qv rows (stride 192: q@0, v@64), kb rows.
__global__ __launch_bounds__(256) void mfma_qkv(
    const float* __restrict__ feat, const ushort* __restrict__ Bfrag,
    const float* __restrict__ bq,
    const float* __restrict__ gamma, const float* __restrict__ beta,
    const float* __restrict__ stats,
    ushort* __restrict__ qvb, ushort* __restrict__ kb,
    int n_nodes)
{
    __shared__ float sc[IN_DIM], sh[IN_DIM];
    int tid = threadIdx.x;
    if (tid < 128) {
        float inv_n = 1.0f / (float)n_nodes;
        float mean = stats[tid] * inv_n;
        float var  = stats[128 + tid] * inv_n - mean * mean;
        float s    = gamma[tid] * rsqrtf(var + EPS);
        sc[tid] = s; sh[tid] = beta[tid] - mean * s;
    }

    int w    = tid >> 6;
    int lane = tid & 63;
    int row0 = blockIdx.x * 64;
    int m    = lane & 15;
    int quad = lane >> 4;
    int nm1  = n_nodes - 1;

    short8 bfr[16];
    #pragma unroll
    for (int f = 0; f < 16; f++)
        bfr[f] = *(const short8*)&Bfrag[((w * 16 + f) * 64 + lane) * 8];

    __syncthreads();

    f32x4 acc[4][4] = {};   // [row-tile][col-tile]

    #pragma unroll
    for (int kc = 0; kc < 4; kc++) {
        int koff = kc * 32 + quad * 8;
        float4 sc0 = *(const float4*)&sc[koff];
        float4 sc1 = *(const float4*)&sc[koff + 4];
        float4 sh0 = *(const float4*)&sh[koff];
        float4 sh1 = *(const float4*)&sh[koff + 4];
        short8 afr[4];
        #pragma unroll
        for (int rt = 0; rt < 4; rt++) {
            int row = row0 + rt * 16 + m;
            row = row < nm1 ? row : nm1;            // clamp OOB reads
            const float* fp = &feat[(size_t)row * IN_DIM + koff];
            float4 x0 = *(const float4*)fp;
            float4 x1 = *(const float4*)(fp + 4);
            afr[rt][0] = f2bfs(x0.x * sc0.x + sh0.x);
            afr[rt][1] = f2bfs(x0.y * sc0.y + sh0.y);
            afr[rt][2] = f2bfs(x0.z * sc0.z + sh0.z);
            afr[rt][3] = f2bfs(x0.w * sc0.w + sh0.w);
            afr[rt][4] = f2bfs(x1.x * sc1.x + sh1.x);
            afr[rt][5] = f2bfs(x1.y * sc1.y + sh1.y);
            afr[rt][6] = f2bfs(x1.z * sc1.z + sh1.z);
            afr[rt][7] = f2bfs(x1.w * sc1.w + sh1.w);
        }
        #pragma unroll
        for (int rt = 0; rt < 4; rt++)
            #pragma unroll
            for (int ct = 0; ct < 4; ct++)
                acc[rt][ct] = __builtin_amdgcn_mfma_f32_16x16x32_bf16(
                    afr[rt], bfr[ct * 4 + kc], acc[rt][ct], 0, 0, 0);
    }

    // w==0: q -> qv@0 ; w==1: k -> kb ; w==2/3: v -> qv@64/128
    ushort* base; int ld, cl;
    if (w == 1)      { base = kb;  ld = HID; cl = 0; }
    else             { base = qvb; ld = 192; cl = (w == 0) ? 0 : 64 * (w - 1); }

    #pragma unroll
    for (int ct = 0; ct < 4; ct++) {
        int col = cl + ct * 16 + m;
        float bias = (w == 0) ? bq[ct * 16 + m] : 0.f;
        #pragma unroll
        for (int rt = 0; rt < 4; rt++) {
            int r0 = row0 + rt * 16 + quad * 4;
            #pragma unroll
            for (int r = 0; r < 4; r++)
                base[(size_t)(r0 + r) * ld + col] = f2bf(acc[rt][ct][r] + bias);
        }
    }
}

// ---------------- binning pass 1: per-WG bucket histogram ------------------
// bucket = dst>>6 (64 nodes). LDS counters only; one coalesced-ish dump.
__global__ __launch_bounds__(256) void hist_bins(
    const int* __restrict__ dst, int* __restrict__ histT,
    int n_edges, int nbk, int chunk)
{
    extern __shared__ int cnt[];              // nbk ints
    int w = blockIdx.x, t = threadIdx.x;
    for (int b = t; b < nbk; b += 256) cnt[b] = 0;
    __syncthreads();
    int lo = w * chunk;
    int hi = lo + chunk; if (hi > n_edges) hi = n_edges;
    for (int e = lo + t; e < hi; e += 256)
        atomicAdd(&cnt[dst[e] >> 6], 1);
    __syncthreads();
    for (int b = t; b < nbk; b += 256)
        histT[b * NWG + w] = cnt[b];
}

// ---------------- scan kernels (exclusive scan of histT) -------------------
__global__ __launch_bounds__(256) void scan_partial(
    const int* __restrict__ deg, int* __restrict__ part, int n)
{
    int chunk = (n + SCAN_B - 1) / SCAN_B;
    int lo = blockIdx.x * chunk;
    int hi = lo + chunk; if (hi > n) hi = n;
    int s = 0;
    for (int i = lo + threadIdx.x; i < hi; i += 256) s += deg[i];
    __shared__ int red[256];
    red[threadIdx.x] = s; __syncthreads();
    for (int d = 128; d; d >>= 1) {
        if (threadIdx.x < d) red[threadIdx.x] += red[threadIdx.x + d];
        __syncthreads();
    }
    if (threadIdx.x == 0) part[blockIdx.x] = red[0];
}

__global__ __launch_bounds__(256) void scan_combine(
    int* __restrict__ part, int* __restrict__ offsets, int n)
{
    __shared__ int tmp[256];
    int t = threadIdx.x;
    int v = part[t];
    tmp[t] = v; __syncthreads();
    for (int d = 1; d < 256; d <<= 1) {
        int cur = tmp[t];
        int add = (t >= d) ? tmp[t - d] : 0;
        __syncthreads();
        tmp[t] = cur + add;
        __syncthreads();
    }
    part[t] = tmp[t] - v;
    if (t == 255) offsets[n] = tmp[255];
}

__global__ __launch_bounds__(256) void scan_final(
    const int* __restrict__ deg, const int* __restrict__ part,
    int* __restrict__ offsets, int* __restrict__ cursor, int n)
{
    __shared__ int tmp[256];
    int t = threadIdx.x;
    int chunk = (n + SCAN_B - 1) / SCAN_B;
    int lo = blockIdx.x * chunk;
    int hi = lo + chunk; if (hi > n) hi = n;
    int base = part[blockIdx.x];
    for (int i0 = lo; i0 < hi; i0 += 256) {
        int i = i0 + t;
        int d = (i < hi) ? deg[i] : 0;
        tmp[t] = d; __syncthreads();
        for (int s = 1; s < 256; s <<= 1) {
            int cur = tmp[t];
            int add = (t >= s) ? tmp[t - s] : 0;
            __syncthreads();
            tmp[t] = cur + add;
            __syncthreads();
        }
        int excl = tmp[t] - d;
        int total = tmp[255];
        if (i < hi) { offsets[i] = base + excl; cursor[i] = base + excl; }
        base += total;
        __syncthreads();
    }
}

// ---------------- binning pass 2: deterministic scatter --------------------
// Each WG writes into its PRIVATE per-bucket segments (offs[b*NWG+w]) via
// LDS cursors -> no global atomics; ~16-entry sequential runs per segment
// keep writes line-efficient. packed = (dst&63)<<26 | src.
__global__ __launch_bounds__(256) void scatter_bins(
    const int* __restrict__ src, const int* __restrict__ dst,
    const int* __restrict__ offs, int* __restrict__ packed,
    int n_edges, int nbk, int chunk)
{
    extern __shared__ int cur[];              // nbk ints
    int w = blockIdx.x, t = threadIdx.x;
    for (int b = t; b < nbk; b += 256) cur[b] = offs[b * NWG + w];
    __syncthreads();
    int lo = w * chunk;
    int hi = lo + chunk; if (hi > n_edges) hi = n_edges;
    for (int e = lo + t; e < hi; e += 256) {
        int d = dst[e];
        int b = d >> 6;
        int pos = atomicAdd(&cur[b], 1);      // LDS atomic
        packed[pos] = (int)(((unsigned)(d & 63) << 26) | (unsigned)src[e]);
    }
}

// ---------------- fused gather: LDS ELL build + per-node core --------------
// lane = sub*16 + h : sub in [0,4) picks the edge, h in [0,16) picks 4 q-dims
// and 8 v-dims. qv row: [q 64 | v 128] bf16, stride 192.
__device__ __forceinline__ void gather_core(
    const int* row, int cnt, int node, int h, int sub,
    const ushort* __restrict__ qvb, const ushort* __restrict__ kb,
    const float* __restrict__ We, float* __restrict__ out)
{
    if (cnt == 0) {
        if (sub == 0) {
            float4 z = make_float4(0.f, 0.f, 0.f, 0.f);
            *(float4*)&out[node * OUT_DIM + 4 * h]      = z;
            *(float4*)&out[node * OUT_DIM + 64 + 4 * h] = z;
        }
        return;
    }

    float4 kd = bf4_to_f4(*(const ushort4*)&kb[node * HID + 4 * h]);
    float4 we = *(const float4*)&We[4 * h];

    float4 o0 = make_float4(0.f, 0.f, 0.f, 0.f);
    float4 o1 = make_float4(0.f, 0.f, 0.f, 0.f);
    float ssum = 0.f;

    for (int p0 = 0; p0 < cnt; p0 += 4) {
        int p = p0 + sub;
        bool act = (p < cnt);
        int sN = row[act ? p : 0];
        const ushort* qv = qvb + (size_t)sN * 192;
        float4 qq = bf4_to_f4(*(const ushort4*)(qv + 4 * h));
        float t;
        t  = we.x * __fdividef(1.f, 1.f + __expf(-(qq.x + kd.x)));
        t += we.y * __fdividef(1.f, 1.f + __expf(-(qq.y + kd.y)));
        t += we.z * __fdividef(1.f, 1.f + __expf(-(qq.z + kd.z)));
        t += we.w * __fdividef(1.f, 1.f + __expf(-(qq.w + kd.w)));
        t += __shfl_xor(t, 1);
        t += __shfl_xor(t, 2);
        t += __shfl_xor(t, 4);
        t += __shfl_xor(t, 8);
        float exv = act ? __expf(t) : 0.f;
        ssum += exv;
        float4 v0 = bf4_to_f4(*(const ushort4*)(qv + 64 + 4 * h));
        float4 v1 = bf4_to_f4(*(const ushort4*)(qv + 128 + 4 * h));
        o0.x += exv * v0.x; o0.y += exv * v0.y;
        o0.z += exv * v0.z; o0.w += exv * v0.w;
        o1.x += exv * v1.x; o1.y += exv * v1.y;
        o1.z += exv * v1.z; o1.w += exv * v1.w;
    }

    ssum += __shfl_xor(ssum, 16); ssum += __shfl_xor(ssum, 32);
    o0.x += __shfl_xor(o0.x, 16); o0.x += __shfl_xor(o0.x, 32);
    o0.y += __shfl_xor(o0.y, 16); o0.y += __shfl_xor(o0.y, 32);
    o0.z += __shfl_xor(o0.z, 16); o0.z += __shfl_xor(o0.z, 32);
    o0.w += __shfl_xor(o0.w, 16); o0.w += __shfl_xor(o0.w, 32);
    o1.x += __shfl_xor(o1.x, 16); o1.x += __shfl_xor(o1.x, 32);
    o1.y += __shfl_xor(o1.y, 16); o1.y += __shfl_xor(o1.y, 32);
    o1.z += __shfl_xor(o1.z, 16); o1.z += __shfl_xor(o1.z, 32);
    o1.w += __shfl_xor(o1.w, 16); o1.w += __shfl_xor(o1.w, 32);

    if (sub == 0) {
        float inv = (ssum > 0.f) ? __fdividef(1.f, ssum) : 0.f;
        o0.x *= inv; o0.y *= inv; o0.z *= inv; o0.w *= inv;
        o1.x *= inv; o1.y *= inv; o1.z *= inv; o1.w *= inv;
        *(float4*)&out[node * OUT_DIM + 4 * h]      = o0;
        *(float4*)&out[node * OUT_DIM + 64 + 4 * h] = o1;
    }
}

__global__ __launch_bounds__(256) void gather_fused(
    const int* __restrict__ offs, const int* __restrict__ packed,
    const ushort* __restrict__ qvb, const ushort* __restrict__ kb,
    const float* __restrict__ We,
    float* __restrict__ out, int n_nodes)
{
    __shared__ int deg_l[64];
    __shared__ int ell_l[64][ELL_W];          // 16 KB
    int b = blockIdx.x;
    int t = threadIdx.x;
    if (t < 64) deg_l[t] = 0;
    __syncthreads();

    int beg = offs[b * NWG];
    int end = offs[(b + 1) * NWG];
    for (int e = beg + t; e < end; e += 256) {
        int p = packed[e];
        int dl = (int)((unsigned)p >> 26);
        int pos = atomicAdd(&deg_l[dl], 1);   // LDS atomic
        if (pos < ELL_W) ell_l[dl][pos] = p & 0x03FFFFFF;
    }
    __syncthreads();

    int wv   = t >> 6;
    int lane = t & 63;
    int h    = lane & 15;
    int sub  = lane >> 4;
    #pragma unroll 1
    for (int i = 0; i < 16; i++) {
        int dl = wv * 16 + i;
        int node = (b << 6) + dl;
        if (node >= n_nodes) break;
        int cnt = deg_l[dl];
        cnt = cnt < ELL_W ? cnt : ELL_W;
        gather_core(&ell_l[dl][0], cnt, node, h, sub, qvb, kb, We, out);
    }
}

extern "C" void kernel_launch(void* const* d_in, const int* in_sizes, int n_in,
                              void* d_out, int out_size, void* d_ws, size_t ws_size,
                              hipStream_t stream)
{
    const float* feat  = (const float*)d_in[0];
    const int*   src   = (const int*)d_in[1];
    const int*   dst   = (const int*)d_in[2];
    const float* gamma = (const float*)d_in[3];
    const float* beta  = (const float*)d_in[4];
    const float* Wq    = (const float*)d_in[5];
    const float* bq    = (const float*)d_in[6];
    const float* Wk    = (const float*)d_in[7];
    const float* Wv    = (const float*)d_in[8];
    const float* We    = (const float*)d_in[9];

    int n_nodes = in_sizes[0] / IN_DIM;
    int n_edges = in_sizes[1];
    int n_pad   = n_nodes + 64;             // store slack for branchless epilogue
    int nbk     = (n_nodes + 63) >> 6;      // 64-node buckets
    int nidx    = nbk * NWG;                // hist/offs matrix size
    int chunk   = (n_edges + NWG - 1) / NWG;

    float* ws = (float*)d_ws;

    // ---- workspace carve-up (ints after 256 stats floats) ----
    int* histT  = (int*)(ws + 256);
    int* offs   = histT + nidx;             // nidx+1 entries
    int* part   = offs + nidx + 1;          // SCAN_B
    int* cursor = part + SCAN_B;            // nidx+1 (scan_final scratch)
    int* packed = cursor + nidx + 1;        // n_edges
    size_t off = 256 + (size_t)(nidx) + (nidx + 1) + SCAN_B + (nidx + 1)
               + (size_t)n_edges;
    off = (off + 3) & ~(size_t)3;
    ushort* qvb   = (ushort*)(ws + off);
    ushort* kb    = qvb + (size_t)n_pad * 192;
    ushort* Bfrag = kb + (size_t)n_pad * HID;

    size_t lds_bins = (size_t)nbk * sizeof(int);

    hipMemsetAsync(ws, 0, 256 * sizeof(float), stream);
    stats_kernel<<<256, 256, 0, stream>>>(feat, ws, n_nodes);
    wprep<<<16, 256, 0, stream>>>(Wq, Wk, Wv, Bfrag);
    hist_bins<<<NWG, 256, lds_bins, stream>>>(dst, histT, n_edges, nbk, chunk);
    scan_partial<<<SCAN_B, 256, 0, stream>>>(histT, part, nidx);
    scan_combine<<<1, 256, 0, stream>>>(part, offs, nidx);
    scan_final<<<SCAN_B, 256, 0, stream>>>(histT, part, offs, cursor, nidx);
    scatter_bins<<<NWG, 256, lds_bins, stream>>>(
        src, dst, offs, packed, n_edges, nbk, chunk);
    mfma_qkv<<<(n_nodes + 63) / 64, 256, 0, stream>>>(
        feat, Bfrag, bq, gamma, beta, ws, qvb, kb, n_nodes);
    gather_fused<<<nbk, 256, 0, stream>>>(
        offs, packed, qvb, kb, We, (float*)d_out, n_nodes);
}

// Round 6
// 429.664 us; speedup vs baseline: 1.4884x; 1.1379x over previous
//
#include <hip/hip_runtime.h>
#include <math.h>

#define IN_DIM 128
#define HID 64
#define OUT_DIM 128
#define ELL_W 64
#define BKT 32          // nodes per bucket / per gather block
#define HWG 64          // hist/scatter workgroups
constexpr float EPS = 1e-5f;

typedef short short8 __attribute__((ext_vector_type(8)));
typedef float f32x4  __attribute__((ext_vector_type(4)));

// ---------------------------------------------------------------------------
// ws layout:
//   float [0,256)   column sums / sum-of-squares
//   int   bcnt[nbk]      per-bucket edge counts (bucket = dst>>5)
//   int   offs[nbk+1]    exclusive scan (immutable, for gather)
//   int   cursor[nbk]    scatter reservation cursors
//   int   packed[n_edges]  (dst&31)<<26 | src, grouped by bucket
//   bf16  qv[(N+64)*192] (q 64 | v 128 per row, 384B), kb[(N+64)*64]
//   bf16  Bfrag[64*64*8]
// Edge pipeline: zero per-edge global atomics; scatter writes are compact runs.
// ---------------------------------------------------------------------------

__device__ inline ushort f2bf(float x) {          // RNE float->bf16 bits
    __bf16 h = (__bf16)x;
    return *reinterpret_cast<ushort*>(&h);
}
__device__ inline short f2bfs(float x) {
    __bf16 h = (__bf16)x;
    return *reinterpret_cast<short*>(&h);
}
__device__ inline float bf2f(ushort u) {
    union { unsigned u; float f; } c; c.u = ((unsigned)u) << 16;
    return c.f;
}
__device__ inline float4 bf4_to_f4(ushort4 u) {
    return make_float4(bf2f(u.x), bf2f(u.y), bf2f(u.z), bf2f(u.w));
}

// ---------------- fused pre-pass: stats | hist | wprep ---------------------
// blocks [0,256): feat column stats; [256,256+HWG): bucket histogram;
// [256+HWG, +16): weight fragment prep. One dispatch instead of three.
__global__ __launch_bounds__(256) void pre_kernel(
    const float* __restrict__ feat, float* __restrict__ ws, int n_nodes,
    const int* __restrict__ dst, int* __restrict__ bcnt, int n_edges,
    const float* __restrict__ Wq, const float* __restrict__ Wk,
    const float* __restrict__ Wv, ushort* __restrict__ Bfrag,
    int nbk, int chunk)
{
    extern __shared__ int sm[];
    int t = threadIdx.x;

    if (blockIdx.x < 256) {
        // ---- stats ----
        float* redS = (float*)sm;          // 256
        float* redQ = redS + 256;          // 256
        int col  = t & 127;
        int half = t >> 7;
        float sum = 0.f, sq = 0.f;
        for (int r = blockIdx.x * 2 + half; r < n_nodes; r += 512) {
            float x = feat[r * IN_DIM + col];
            sum += x; sq += x * x;
        }
        redS[t] = sum; redQ[t] = sq;
        __syncthreads();
        if (t < 128) {
            sum = redS[t] + redS[t + 128];
            sq  = redQ[t] + redQ[t + 128];
            unsafeAtomicAdd(&ws[col], sum);
            unsafeAtomicAdd(&ws[128 + col], sq);
        }
    } else if (blockIdx.x < 256 + HWG) {
        // ---- hist: LDS bucket counts -> one global atomic per bucket ----
        int w = blockIdx.x - 256;
        for (int b = t; b < nbk; b += 256) sm[b] = 0;
        __syncthreads();
        int lo = w * chunk;
        int hi = lo + chunk; if (hi > n_edges) hi = n_edges;
        for (int e = lo + t; e < hi; e += 256)
            atomicAdd(&sm[__builtin_nontemporal_load(dst + e) >> 5], 1);
        __syncthreads();
        for (int b = t; b < nbk; b += 256)
            if (sm[b]) atomicAdd(&bcnt[b], sm[b]);
    } else {
        // ---- wprep ----
        int gid  = (blockIdx.x - 256 - HWG) * 256 + t;   // 0..4095
        int f    = gid >> 6;
        int lane = gid & 63;
        int kc = f & 3, ct = (f >> 2) & 3, w = f >> 4;
        int col   = w * 64 + ct * 16 + (lane & 15);
        int kbase = kc * 32 + (lane >> 4) * 8;
        ushort tmp[8];
        #pragma unroll
        for (int j = 0; j < 8; j++) {
            int k = kbase + j;
            float val;
            if (col < 64)       val = Wq[k * HID + col];
            else if (col < 128) val = Wk[k * HID + (col - 64)];
            else                val = Wv[k * OUT_DIM + (col - 128)];
            tmp[j] = f2bf(val);
        }
        ushort* d = &Bfrag[(f * 64 + lane) * 8];
        *(ushort4*)d       = make_ushort4(tmp[0], tmp[1], tmp[2], tmp[3]);
        *(ushort4*)(d + 4) = make_ushort4(tmp[4], tmp[5], tmp[6], tmp[7]);
    }
}

// ---------------- tiny scan over nbk bucket totals (1 WG) ------------------
__global__ __launch_bounds__(256) void scan_init(
    const int* __restrict__ bcnt, int* __restrict__ offs,
    int* __restrict__ cursor, int n)
{
    __shared__ int tmp[256];
    int t = threadIdx.x;
    int base = 0;
    for (int i0 = 0; i0 < n; i0 += 256) {
        int i = i0 + t;
        int d = (i < n) ? bcnt[i] : 0;
        tmp[t] = d; __syncthreads();
        for (int s = 1; s < 256; s <<= 1) {
            int cur = tmp[t];
            int add = (t >= s) ? tmp[t - s] : 0;
            __syncthreads();
            tmp[t] = cur + add;
            __syncthreads();
        }
        int excl = tmp[t] - d;
        if (i < n) { offs[i] = base + excl; cursor[i] = base + excl; }
        base += tmp[255];
        __syncthreads();
    }
    if (t == 0) offs[n] = base;
}

// ---------------- scatter: per-WG range reservation, no per-edge atomics ---
__global__ __launch_bounds__(512) void scatter_bins(
    const int* __restrict__ src, const int* __restrict__ dst,
    int* __restrict__ cursor, int* __restrict__ packed,
    int n_edges, int nbk, int chunk)
{
    extern __shared__ int sm[];               // cnt[nbk] | base[nbk]
    int* cnt  = sm;
    int* base = sm + nbk;
    int w = blockIdx.x, t = threadIdx.x;
    for (int b = t; b < nbk; b += 512) cnt[b] = 0;
    __syncthreads();
    int lo = w * chunk;
    int hi = lo + chunk; if (hi > n_edges) hi = n_edges;
    // pass A: count
    for (int e = lo + t; e < hi; e += 512)
        atomicAdd(&cnt[__builtin_nontemporal_load(dst + e) >> 5], 1);
    __syncthreads();
    // reserve ranges (one global atomic per non-empty bucket per WG)
    for (int b = t; b < nbk; b += 512) {
        int c = cnt[b];
        if (c) base[b] = atomicAdd(&cursor[b], c);
        cnt[b] = 0;
    }
    __syncthreads();
    // pass B: place
    for (int e = lo + t; e < hi; e += 512) {
        int d = __builtin_nontemporal_load(dst + e);
        int s = __builtin_nontemporal_load(src + e);
        int b = d >> 5;
        int pos = base[b] + atomicAdd(&cnt[b], 1);   // LDS atomic
        packed[pos] = (int)(((unsigned)(d & 31) << 26) | (unsigned)s);
    }
}

// MFMA layernorm+GEMM. Output layout: qv rows (stride 192: q@0, v@64), kb rows.
__global__ __launch_bounds__(256) void mfma_qkv(
    const float* __restrict__ feat, const ushort* __restrict__ Bfrag,
    const float* __restrict__ bq,
    const float* __restrict__ gamma, const float* __restrict__ beta,
    const float* __restrict__ stats,
    ushort* __restrict__ qvb, ushort* __restrict__ kb,
    int n_nodes)
{
    __shared__ float sc[IN_DIM], sh[IN_DIM];
    int tid = threadIdx.x;
    if (tid < 128) {
        float inv_n = 1.0f / (float)n_nodes;
        float mean = stats[tid] * inv_n;
        float var  = stats[128 + tid] * inv_n - mean * mean;
        float s    = gamma[tid] * rsqrtf(var + EPS);
        sc[tid] = s; sh[tid] = beta[tid] - mean * s;
    }

    int w    = tid >> 6;
    int lane = tid & 63;
    int row0 = blockIdx.x * 64;
    int m    = lane & 15;
    int quad = lane >> 4;
    int nm1  = n_nodes - 1;

    short8 bfr[16];
    #pragma unroll
    for (int f = 0; f < 16; f++)
        bfr[f] = *(const short8*)&Bfrag[((w * 16 + f) * 64 + lane) * 8];

    __syncthreads();

    f32x4 acc[4][4] = {};   // [row-tile][col-tile]

    #pragma unroll
    for (int kc = 0; kc < 4; kc++) {
        int koff = kc * 32 + quad * 8;
        float4 sc0 = *(const float4*)&sc[koff];
        float4 sc1 = *(const float4*)&sc[koff + 4];
        float4 sh0 = *(const float4*)&sh[koff];
        float4 sh1 = *(const float4*)&sh[koff + 4];
        short8 afr[4];
        #pragma unroll
        for (int rt = 0; rt < 4; rt++) {
            int row = row0 + rt * 16 + m;
            row = row < nm1 ? row : nm1;            // clamp OOB reads
            const float* fp = &feat[(size_t)row * IN_DIM + koff];
            float4 x0 = *(const float4*)fp;
            float4 x1 = *(const float4*)(fp + 4);
            afr[rt][0] = f2bfs(x0.x * sc0.x + sh0.x);
            afr[rt][1] = f2bfs(x0.y * sc0.y + sh0.y);
            afr[rt][2] = f2bfs(x0.z * sc0.z + sh0.z);
            afr[rt][3] = f2bfs(x0.w * sc0.w + sh0.w);
            afr[rt][4] = f2bfs(x1.x * sc1.x + sh1.x);
            afr[rt][5] = f2bfs(x1.y * sc1.y + sh1.y);
            afr[rt][6] = f2bfs(x1.z * sc1.z + sh1.z);
            afr[rt][7] = f2bfs(x1.w * sc1.w + sh1.w);
        }
        #pragma unroll
        for (int rt = 0; rt < 4; rt++)
            #pragma unroll
            for (int ct = 0; ct < 4; ct++)
                acc[rt][ct] = __builtin_amdgcn_mfma_f32_16x16x32_bf16(
                    afr[rt], bfr[ct * 4 + kc], acc[rt][ct], 0, 0, 0);
    }

    // w==0: q -> qv@0 ; w==1: k -> kb ; w==2/3: v -> qv@64/128
    ushort* base; int ld, cl;
    if (w == 1)      { base = kb;  ld = HID; cl = 0; }
    else             { base = qvb; ld = 192; cl = (w == 0) ? 0 : 64 * (w - 1); }

    #pragma unroll
    for (int ct = 0; ct < 4; ct++) {
        int col = cl + ct * 16 + m;
        float bias = (w == 0) ? bq[ct * 16 + m] : 0.f;
        #pragma unroll
        for (int rt = 0; rt < 4; rt++) {
            int r0 = row0 + rt * 16 + quad * 4;
            #pragma unroll
            for (int r = 0; r < 4; r++)
                base[(size_t)(r0 + r) * ld + col] = f2bf(acc[rt][ct][r] + bias);
        }
    }
}

// ---------------- fused gather: LDS ELL build + per-node core --------------
// lane = sub*16 + h : sub in [0,4) picks the edge, h in [0,16) picks 4 q-dims
// and 8 v-dims. qv row: [q 64 | v 128] bf16, stride 192.
__device__ __forceinline__ void gather_core(
    const int* row, int cnt, int node, int h, int sub,
    const ushort* __restrict__ qvb, const ushort* __restrict__ kb,
    const float* __restrict__ We, float* __restrict__ out)
{
    if (cnt == 0) {
        if (sub == 0) {
            float4 z = make_float4(0.f, 0.f, 0.f, 0.f);
            *(float4*)&out[node * OUT_DIM + 4 * h]      = z;
            *(float4*)&out[node * OUT_DIM + 64 + 4 * h] = z;
        }
        return;
    }

    float4 kd = bf4_to_f4(*(const ushort4*)&kb[node * HID + 4 * h]);
    float4 we = *(const float4*)&We[4 * h];

    float4 o0 = make_float4(0.f, 0.f, 0.f, 0.f);
    float4 o1 = make_float4(0.f, 0.f, 0.f, 0.f);
    float ssum = 0.f;

    for (int p0 = 0; p0 < cnt; p0 += 4) {
        int p = p0 + sub;
        bool act = (p < cnt);
        int sN = row[act ? p : 0];
        const ushort* qv = qvb + (size_t)sN * 192;
        float4 qq = bf4_to_f4(*(const ushort4*)(qv + 4 * h));
        float t;
        t  = we.x * __fdividef(1.f, 1.f + __expf(-(qq.x + kd.x)));
        t += we.y * __fdividef(1.f, 1.f + __expf(-(qq.y + kd.y)));
        t += we.z * __fdividef(1.f, 1.f + __expf(-(qq.z + kd.z)));
        t += we.w * __fdividef(1.f, 1.f + __expf(-(qq.w + kd.w)));
        t += __shfl_xor(t, 1);
        t += __shfl_xor(t, 2);
        t += __shfl_xor(t, 4);
        t += __shfl_xor(t, 8);
        float exv = act ? __expf(t) : 0.f;
        ssum += exv;
        float4 v0 = bf4_to_f4(*(const ushort4*)(qv + 64 + 4 * h));
        float4 v1 = bf4_to_f4(*(const ushort4*)(qv + 128 + 4 * h));
        o0.x += exv * v0.x; o0.y += exv * v0.y;
        o0.z += exv * v0.z; o0.w += exv * v0.w;
        o1.x += exv * v1.x; o1.y += exv * v1.y;
        o1.z += exv * v1.z; o1.w += exv * v1.w;
    }

    ssum += __shfl_xor(ssum, 16); ssum += __shfl_xor(ssum, 32);
    o0.x += __shfl_xor(o0.x, 16); o0.x += __shfl_xor(o0.x, 32);
    o0.y += __shfl_xor(o0.y, 16); o0.y += __shfl_xor(o0.y, 32);
    o0.z += __shfl_xor(o0.z, 16); o0.z += __shfl_xor(o0.z, 32);
    o0.w += __shfl_xor(o0.w, 16); o0.w += __shfl_xor(o0.w, 32);
    o1.x += __shfl_xor(o1.x, 16); o1.x += __shfl_xor(o1.x, 32);
    o1.y += __shfl_xor(o1.y, 16); o1.y += __shfl_xor(o1.y, 32);
    o1.z += __shfl_xor(o1.z, 16); o1.z += __shfl_xor(o1.z, 32);
    o1.w += __shfl_xor(o1.w, 16); o1.w += __shfl_xor(o1.w, 32);

    if (sub == 0) {
        float inv = (ssum > 0.f) ? __fdividef(1.f, ssum) : 0.f;
        o0.x *= inv; o0.y *= inv; o0.z *= inv; o0.w *= inv;
        o1.x *= inv; o1.y *= inv; o1.z *= inv; o1.w *= inv;
        *(float4*)&out[node * OUT_DIM + 4 * h]      = o0;
        *(float4*)&out[node * OUT_DIM + 64 + 4 * h] = o1;
    }
}

__global__ __launch_bounds__(256) void gather_fused(
    const int* __restrict__ offs, const int* __restrict__ packed,
    const ushort* __restrict__ qvb, const ushort* __restrict__ kb,
    const float* __restrict__ We,
    float* __restrict__ out, int n_nodes)
{
    __shared__ int deg_l[BKT];
    __shared__ int ell_l[BKT][ELL_W];         // 8 KB
    int b = blockIdx.x;
    int t = threadIdx.x;
    if (t < BKT) deg_l[t] = 0;
    __syncthreads();

    int beg = offs[b];
    int end = offs[b + 1];
    for (int e = beg + t; e < end; e += 256) {
        int p = packed[e];
        int dl = (int)((unsigned)p >> 26);
        int pos = atomicAdd(&deg_l[dl], 1);   // LDS atomic
        if (pos < ELL_W) ell_l[dl][pos] = p & 0x03FFFFFF;
    }
    __syncthreads();

    int wv   = t >> 6;
    int lane = t & 63;
    int h    = lane & 15;
    int sub  = lane >> 4;
    #pragma unroll 1
    for (int i = 0; i < BKT / 4; i++) {
        int dl = wv * (BKT / 4) + i;
        int node = b * BKT + dl;
        if (node >= n_nodes) break;
        int cnt = deg_l[dl];
        cnt = cnt < ELL_W ? cnt : ELL_W;
        gather_core(&ell_l[dl][0], cnt, node, h, sub, qvb, kb, We, out);
    }
}

extern "C" void kernel_launch(void* const* d_in, const int* in_sizes, int n_in,
                              void* d_out, int out_size, void* d_ws, size_t ws_size,
                              hipStream_t stream)
{
    const float* feat  = (const float*)d_in[0];
    const int*   src   = (const int*)d_in[1];
    const int*   dst   = (const int*)d_in[2];
    const float* gamma = (const float*)d_in[3];
    const float* beta  = (const float*)d_in[4];
    const float* Wq    = (const float*)d_in[5];
    const float* bq    = (const float*)d_in[6];
    const float* Wk    = (const float*)d_in[7];
    const float* Wv    = (const float*)d_in[8];
    const float* We    = (const float*)d_in[9];

    int n_nodes = in_sizes[0] / IN_DIM;
    int n_edges = in_sizes[1];
    int n_pad   = n_nodes + 64;             // store slack for branchless epilogue
    int nbk     = (n_nodes + BKT - 1) / BKT;
    int chunk   = (n_edges + HWG - 1) / HWG;

    float* ws = (float*)d_ws;

    // ---- workspace carve-up ----
    int* bcnt   = (int*)(ws + 256);
    int* offs   = bcnt + nbk;               // nbk+1
    int* cursor = offs + nbk + 1;           // nbk
    int* packed = cursor + nbk;             // n_edges
    size_t off = 256 + (size_t)nbk + (nbk + 1) + nbk + (size_t)n_edges;
    off = (off + 3) & ~(size_t)3;
    ushort* qvb   = (ushort*)(ws + off);
    ushort* kb    = qvb + (size_t)n_pad * 192;
    ushort* Bfrag = kb + (size_t)n_pad * HID;

    size_t lds_pre  = (size_t)(nbk > 512 ? nbk : 512) * sizeof(int);
    size_t lds_scat = 2 * (size_t)nbk * sizeof(int);

    hipMemsetAsync(ws, 0, (256 + (size_t)nbk) * sizeof(float), stream);
    pre_kernel<<<256 + HWG + 16, 256, lds_pre, stream>>>(
        feat, ws, n_nodes, dst, bcnt, n_edges, Wq, Wk, Wv, Bfrag, nbk, chunk);
    scan_init<<<1, 256, 0, stream>>>(bcnt, offs, cursor, nbk);
    scatter_bins<<<HWG, 512, lds_scat, stream>>>(
        src, dst, cursor, packed, n_edges, nbk, chunk);
    mfma_qkv<<<(n_nodes + 63) / 64, 256, 0, stream>>>(
        feat, Bfrag, bq, gamma, beta, ws, qvb, kb, n_nodes);
    gather_fused<<<nbk, 256, 0, stream>>>(
        offs, packed, qvb, kb, We, (float*)d_out, n_nodes);
}

// Round 8
// 409.481 us; speedup vs baseline: 1.5617x; 1.0493x over previous
//
#include <hip/hip_runtime.h>
#include <math.h>

#define IN_DIM 128
#define HID 64
#define OUT_DIM 128
#define ELL_W 64
#define FA 512          // fill blocks in preA
#define FB 512          // fill blocks in fusedB
constexpr float EPS = 1e-5f;

typedef short short8 __attribute__((ext_vector_type(8)));
typedef float f32x4  __attribute__((ext_vector_type(4)));
typedef int   i32x4  __attribute__((ext_vector_type(4)));

// ---------------------------------------------------------------------------
// ws layout:
//   float [0,256)   column sums / sum-of-squares
//   int   deg[N], ell[N*64]
//   bf16  qv[(N+64)*192] (q 64 | v 128 per row, 384B rows), kb[(N+64)*64]
//   bf16  Bfrag[64*64*8]
// Schedule: memset -> preA(stats||wprep||fill[0,E1)) ->
//           fusedB(mfma||fill[E1,E)) -> gather.
// fill is latency/write-bound with all pipes idle (r0 PMC) -> hide it under
// the BW-bound stats pass and the MFMA-bound qkv pass instead of speeding it.
// ---------------------------------------------------------------------------

__device__ inline ushort f2bf(float x) {          // RNE float->bf16 bits
    __bf16 h = (__bf16)x;
    return *reinterpret_cast<ushort*>(&h);
}
__device__ inline short f2bfs(float x) {
    __bf16 h = (__bf16)x;
    return *reinterpret_cast<short*>(&h);
}
__device__ inline float bf2f(ushort u) {
    union { unsigned u; float f; } c; c.u = ((unsigned)u) << 16;
    return c.f;
}
__device__ inline float4 bf4_to_f4(ushort4 u) {
    return make_float4(bf2f(u.x), bf2f(u.y), bf2f(u.z), bf2f(u.w));
}

// ---------------- shared fill core: edges [e0,e1), e0 % 4 == 0 -------------
__device__ __forceinline__ void fill_edges(
    const int* __restrict__ src, const int* __restrict__ dst,
    int* __restrict__ deg, int* __restrict__ ell,
    int e0, int e1, int bid, int nblk)
{
    int idx    = bid * 256 + threadIdx.x;
    int stride = nblk * 256;
    int nv     = (e1 - e0) >> 2;
    const i32x4* d4p = reinterpret_cast<const i32x4*>(dst + e0);
    const i32x4* s4p = reinterpret_cast<const i32x4*>(src + e0);

    for (int i = idx; i < nv; i += stride) {
        i32x4 d4 = __builtin_nontemporal_load(d4p + i);
        i32x4 s4 = __builtin_nontemporal_load(s4p + i);
        #pragma unroll
        for (int j = 0; j < 4; j++) {
            int d = d4[j];
            int pos = atomicAdd(&deg[d], 1);
            if (pos < ELL_W) ell[(size_t)d * ELL_W + pos] = s4[j];
        }
    }
    for (int e = e0 + (nv << 2) + idx; e < e1; e += stride) {
        int d = dst[e];
        int pos = atomicAdd(&deg[d], 1);
        if (pos < ELL_W) ell[(size_t)d * ELL_W + pos] = src[e];
    }
}

// ---------------- preA: stats | wprep | fill[0,E1) -------------------------
__global__ __launch_bounds__(256) void preA(
    const float* __restrict__ feat, float* __restrict__ ws, int n_nodes,
    const float* __restrict__ Wq, const float* __restrict__ Wk,
    const float* __restrict__ Wv, ushort* __restrict__ Bfrag,
    const int* __restrict__ src, const int* __restrict__ dst,
    int* __restrict__ deg, int* __restrict__ ell, int e1)
{
    int t = threadIdx.x;
    if (blockIdx.x < 256) {
        // ---- stats ----
        __shared__ float redS[256], redQ[256];
        int col  = t & 127;
        int half = t >> 7;
        float sum = 0.f, sq = 0.f;
        for (int r = blockIdx.x * 2 + half; r < n_nodes; r += 512) {
            float x = feat[r * IN_DIM + col];
            sum += x; sq += x * x;
        }
        redS[t] = sum; redQ[t] = sq;
        __syncthreads();
        if (t < 128) {
            sum = redS[t] + redS[t + 128];
            sq  = redQ[t] + redQ[t + 128];
            unsafeAtomicAdd(&ws[col], sum);
            unsafeAtomicAdd(&ws[128 + col], sq);
        }
    } else if (blockIdx.x < 256 + 16) {
        // ---- wprep ----
        int gid  = (blockIdx.x - 256) * 256 + t;     // 0..4095
        int f    = gid >> 6;
        int lane = gid & 63;
        int kc = f & 3, ct = (f >> 2) & 3, w = f >> 4;
        int col   = w * 64 + ct * 16 + (lane & 15);
        int kbase = kc * 32 + (lane >> 4) * 8;
        ushort tmp[8];
        #pragma unroll
        for (int j = 0; j < 8; j++) {
            int k = kbase + j;
            float val;
            if (col < 64)       val = Wq[k * HID + col];
            else if (col < 128) val = Wk[k * HID + (col - 64)];
            else                val = Wv[k * OUT_DIM + (col - 128)];
            tmp[j] = f2bf(val);
        }
        ushort* d = &Bfrag[(f * 64 + lane) * 8];
        *(ushort4*)d       = make_ushort4(tmp[0], tmp[1], tmp[2], tmp[3]);
        *(ushort4*)(d + 4) = make_ushort4(tmp[4], tmp[5], tmp[6], tmp[7]);
    } else {
        fill_edges(src, dst, deg, ell, 0, e1, blockIdx.x - 272, FA);
    }
}

// ---------------- fusedB: mfma_qkv | fill[E1,E) ----------------------------
// qv rows (stride 192: q@0, v@64), kb rows.
__global__ __launch_bounds__(256) void fusedB(
    const float* __restrict__ feat, const ushort* __restrict__ Bfrag,
    const float* __restrict__ bq,
    const float* __restrict__ gamma, const float* __restrict__ beta,
    const float* __restrict__ stats,
    ushort* __restrict__ qvb, ushort* __restrict__ kb, int n_nodes,
    const int* __restrict__ src, const int* __restrict__ dst,
    int* __restrict__ deg, int* __restrict__ ell, int e1, int n_edges,
    int mb)
{
    if (blockIdx.x >= mb) {
        fill_edges(src, dst, deg, ell, e1, n_edges, blockIdx.x - mb, FB);
        return;
    }

    __shared__ float sc[IN_DIM], sh[IN_DIM];
    int tid = threadIdx.x;
    if (tid < 128) {
        float inv_n = 1.0f / (float)n_nodes;
        float mean = stats[tid] * inv_n;
        float var  = stats[128 + tid] * inv_n - mean * mean;
        float s    = gamma[tid] * rsqrtf(var + EPS);
        sc[tid] = s; sh[tid] = beta[tid] - mean * s;
    }

    int w    = tid >> 6;
    int lane = tid & 63;
    int row0 = blockIdx.x * 64;
    int m    = lane & 15;
    int quad = lane >> 4;
    int nm1  = n_nodes - 1;

    short8 bfr[16];
    #pragma unroll
    for (int f = 0; f < 16; f++)
        bfr[f] = *(const short8*)&Bfrag[((w * 16 + f) * 64 + lane) * 8];

    __syncthreads();

    f32x4 acc[4][4] = {};   // [row-tile][col-tile]

    #pragma unroll
    for (int kc = 0; kc < 4; kc++) {
        int koff = kc * 32 + quad * 8;
        float4 sc0 = *(const float4*)&sc[koff];
        float4 sc1 = *(const float4*)&sc[koff + 4];
        float4 sh0 = *(const float4*)&sh[koff];
        float4 sh1 = *(const float4*)&sh[koff + 4];
        short8 afr[4];
        #pragma unroll
        for (int rt = 0; rt < 4; rt++) {
            int row = row0 + rt * 16 + m;
            row = row < nm1 ? row : nm1;            // clamp OOB reads
            const float* fp = &feat[(size_t)row * IN_DIM + koff];
            float4 x0 = *(const float4*)fp;
            float4 x1 = *(const float4*)(fp + 4);
            afr[rt][0] = f2bfs(x0.x * sc0.x + sh0.x);
            afr[rt][1] = f2bfs(x0.y * sc0.y + sh0.y);
            afr[rt][2] = f2bfs(x0.z * sc0.z + sh0.z);
            afr[rt][3] = f2bfs(x0.w * sc0.w + sh0.w);
            afr[rt][4] = f2bfs(x1.x * sc1.x + sh1.x);
            afr[rt][5] = f2bfs(x1.y * sc1.y + sh1.y);
            afr[rt][6] = f2bfs(x1.z * sc1.z + sh1.z);
            afr[rt][7] = f2bfs(x1.w * sc1.w + sh1.w);
        }
        #pragma unroll
        for (int rt = 0; rt < 4; rt++)
            #pragma unroll
            for (int ct = 0; ct < 4; ct++)
                acc[rt][ct] = __builtin_amdgcn_mfma_f32_16x16x32_bf16(
                    afr[rt], bfr[ct * 4 + kc], acc[rt][ct], 0, 0, 0);
    }

    // w==0: q -> qv@0 ; w==1: k -> kb ; w==2/3: v -> qv@64/128
    ushort* base; int ld, cl;
    if (w == 1)      { base = kb;  ld = HID; cl = 0; }
    else             { base = qvb; ld = 192; cl = (w == 0) ? 0 : 64 * (w - 1); }

    #pragma unroll
    for (int ct = 0; ct < 4; ct++) {
        int col = cl + ct * 16 + m;
        float bias = (w == 0) ? bq[ct * 16 + m] : 0.f;
        #pragma unroll
        for (int rt = 0; rt < 4; rt++) {
            int r0 = row0 + rt * 16 + quad * 4;
            #pragma unroll
            for (int r = 0; r < 4; r++)
                base[(size_t)(r0 + r) * ld + col] = f2bf(acc[rt][ct][r] + bias);
        }
    }
}

// ---------------- gather: 4-edge groups x 16 dims, global ELL --------------
// lane = sub*16 + h. qv row: [q 64 | v 128] bf16, stride 192.
// we is pre-scaled by log2(e) so exp(t) becomes a bare v_exp (exp2f).
__global__ __launch_bounds__(256) void gather_ell(
    const int* __restrict__ deg, const int* __restrict__ ell,
    const ushort* __restrict__ qvb, const ushort* __restrict__ kb,
    const float* __restrict__ We,
    float* __restrict__ out, int n_nodes)
{
    int node = (blockIdx.x * 256 + threadIdx.x) >> 6;
    int lane = threadIdx.x & 63;
    if (node >= n_nodes) return;
    int h   = lane & 15;
    int sub = lane >> 4;
    int cnt = deg[node];
    cnt = cnt < ELL_W ? cnt : ELL_W;

    if (cnt == 0) {
        if (sub == 0) {
            float4 z = make_float4(0.f, 0.f, 0.f, 0.f);
            *(float4*)&out[node * OUT_DIM + 4 * h]      = z;
            *(float4*)&out[node * OUT_DIM + 64 + 4 * h] = z;
        }
        return;
    }

    const int* row = &ell[(size_t)node * ELL_W];
    float4 kd = bf4_to_f4(*(const ushort4*)&kb[node * HID + 4 * h]);
    float4 we = *(const float4*)&We[4 * h];
    const float L2E = 1.4426950408889634f;
    we.x *= L2E; we.y *= L2E; we.z *= L2E; we.w *= L2E;

    float4 o0 = make_float4(0.f, 0.f, 0.f, 0.f);
    float4 o1 = make_float4(0.f, 0.f, 0.f, 0.f);
    float ssum = 0.f;

    for (int p0 = 0; p0 < cnt; p0 += 4) {
        int p = p0 + sub;
        bool act = (p < cnt);
        int sN = row[act ? p : 0];
        const ushort* qv = qvb + (size_t)sN * 192;
        float4 qq = bf4_to_f4(*(const ushort4*)(qv + 4 * h));
        float t;
        t  = we.x * __fdividef(1.f, 1.f + __expf(-(qq.x + kd.x)));
        t += we.y * __fdividef(1.f, 1.f + __expf(-(qq.y + kd.y)));
        t += we.z * __fdividef(1.f, 1.f + __expf(-(qq.z + kd.z)));
        t += we.w * __fdividef(1.f, 1.f + __expf(-(qq.w + kd.w)));
        t += __shfl_xor(t, 1);
        t += __shfl_xor(t, 2);
        t += __shfl_xor(t, 4);
        t += __shfl_xor(t, 8);
        float exv = act ? exp2f(t) : 0.f;     // t already includes log2(e)
        ssum += exv;
        float4 v0 = bf4_to_f4(*(const ushort4*)(qv + 64 + 4 * h));
        float4 v1 = bf4_to_f4(*(const ushort4*)(qv + 128 + 4 * h));
        o0.x += exv * v0.x; o0.y += exv * v0.y;
        o0.z += exv * v0.z; o0.w += exv * v0.w;
        o1.x += exv * v1.x; o1.y += exv * v1.y;
        o1.z += exv * v1.z; o1.w += exv * v1.w;
    }

    ssum += __shfl_xor(ssum, 16); ssum += __shfl_xor(ssum, 32);
    o0.x += __shfl_xor(o0.x, 16); o0.x += __shfl_xor(o0.x, 32);
    o0.y += __shfl_xor(o0.y, 16); o0.y += __shfl_xor(o0.y, 32);
    o0.z += __shfl_xor(o0.z, 16); o0.z += __shfl_xor(o0.z, 32);
    o0.w += __shfl_xor(o0.w, 16); o0.w += __shfl_xor(o0.w, 32);
    o1.x += __shfl_xor(o1.x, 16); o1.x += __shfl_xor(o1.x, 32);
    o1.y += __shfl_xor(o1.y, 16); o1.y += __shfl_xor(o1.y, 32);
    o1.z += __shfl_xor(o1.z, 16); o1.z += __shfl_xor(o1.z, 32);
    o1.w += __shfl_xor(o1.w, 16); o1.w += __shfl_xor(o1.w, 32);

    if (sub == 0) {
        float inv = (ssum > 0.f) ? __fdividef(1.f, ssum) : 0.f;
        o0.x *= inv; o0.y *= inv; o0.z *= inv; o0.w *= inv;
        o1.x *= inv; o1.y *= inv; o1.z *= inv; o1.w *= inv;
        *(float4*)&out[node * OUT_DIM + 4 * h]      = o0;
        *(float4*)&out[node * OUT_DIM + 64 + 4 * h] = o1;
    }
}

extern "C" void kernel_launch(void* const* d_in, const int* in_sizes, int n_in,
                              void* d_out, int out_size, void* d_ws, size_t ws_size,
                              hipStream_t stream)
{
    const float* feat  = (const float*)d_in[0];
    const int*   src   = (const int*)d_in[1];
    const int*   dst   = (const int*)d_in[2];
    const float* gamma = (const float*)d_in[3];
    const float* beta  = (const float*)d_in[4];
    const float* Wq    = (const float*)d_in[5];
    const float* bq    = (const float*)d_in[6];
    const float* Wk    = (const float*)d_in[7];
    const float* Wv    = (const float*)d_in[8];
    const float* We    = (const float*)d_in[9];

    int n_nodes = in_sizes[0] / IN_DIM;
    int n_edges = in_sizes[1];
    int n_pad   = n_nodes + 64;             // store slack for branchless epilogue
    int mb      = (n_nodes + 63) / 64;
    int e1      = ((n_edges * 9) / 20) & ~3;   // ~45% of edges in preA

    float* ws = (float*)d_ws;

    // ---- workspace carve-up ----
    int* deg = (int*)(ws + 256);
    int* ell = deg + n_nodes;
    size_t off = 256 + (size_t)n_nodes * (1 + ELL_W);
    off = (off + 3) & ~(size_t)3;
    ushort* qvb   = (ushort*)(ws + off);
    ushort* kb    = qvb + (size_t)n_pad * 192;
    ushort* Bfrag = kb + (size_t)n_pad * HID;

    hipMemsetAsync(ws, 0, (256 + (size_t)n_nodes) * sizeof(float), stream);
    preA<<<256 + 16 + FA, 256, 0, stream>>>(
        feat, ws, n_nodes, Wq, Wk, Wv, Bfrag, src, dst, deg, ell, e1);
    fusedB<<<mb + FB, 256, 0, stream>>>(
        feat, Bfrag, bq, gamma, beta, ws, qvb, kb, n_nodes,
        src, dst, deg, ell, e1, n_edges, mb);
    long long g_threads = (long long)n_nodes * 64;
    gather_ell<<<(int)((g_threads + 255) / 256), 256, 0, stream>>>(
        deg, ell, qvb, kb, We, (float*)d_out, n_nodes);
}